// Round 18
// baseline (891.793 us; speedup 1.0000x reference)
//
#include <hip/hip_runtime.h>

// Problem constants (B=8, N=4096, n_points=1024, n_samples=32, D_PTS=6, MLPS=[64,64,128])
#define NPTS  4096
#define NB    8
#define NC    1024
#define NSAMP 32
#define DP    6
#define C0    9      // 3 + D_PTS
#define C3    128
#define ROWS_TOT 262144   // NB*NC*NSAMP

// Workspace layout (bytes). Requires ws_size >= ~184 MB.
// ws+0..1KB: control (ticket counter @0, prog[b] @ 64+64b), memset each call
#define OFF_SS   (32ull<<10)     // 3 layers x {scale[128], shift[128]}
#define OFF_Y0   (16ull<<20)     // y0: 262144 x 64 f32 (67 MB)
#define OFF_Y1   (96ull<<20)     // y1: 262144 x 64 f32 (67 MB)
#define OFF_PSUM (168ull<<20)    // per-block channel sums   [C][NBLK]
#define OFF_PSQ  (172ull<<20)    // per-block channel sumsq  [C][NBLK]
#define OFF_GMX  (176ull<<20)    // per-centroid channel max [8192][128]
#define OFF_GMN  (180ull<<20)    // per-centroid channel min [8192][128]

typedef unsigned long long ull;
typedef float v2f __attribute__((ext_vector_type(2)));

// DPP move with old=self (masked/invalid lanes keep their value -> fmax identity)
template <int CTRL, int RM>
__device__ __forceinline__ float dpp_mov_f(float x) {
  int xi = __float_as_int(x);
  int r = __builtin_amdgcn_update_dpp(xi, xi, CTRL, RM, 0xf, false);
  return __int_as_float(r);
}

// Canonical gfx9 wave64 f32 max reduce; result valid in lane 63.
__device__ __forceinline__ float wave64_fmax(float x) {
  x = fmaxf(x, dpp_mov_f<0x111, 0xf>(x));  // row_shr:1
  x = fmaxf(x, dpp_mov_f<0x112, 0xf>(x));  // row_shr:2
  x = fmaxf(x, dpp_mov_f<0x114, 0xf>(x));  // row_shr:4
  x = fmaxf(x, dpp_mov_f<0x118, 0xf>(x));  // row_shr:8
  x = fmaxf(x, dpp_mov_f<0x142, 0xa>(x));  // row_bcast:15 -> rows 1,3
  x = fmaxf(x, dpp_mov_f<0x143, 0xc>(x));  // row_bcast:31 -> rows 2,3
  return x;
}

#define BCAP 256

struct FpsShared {
  float4 sxyz[NPTS];          // 64 KB
  float4 wkc[2][4];
  int    wki[2][4];
  int    sidx[NC];            // 4 KB
};
struct BallShared {
  ull skeys[BCAP];
  ull ssorted[BCAP];
  int sel[NSAMP];
  float xs0[NSAMP * C0];
  float w0s[C0 * 64];
  float b0s[64];
  float red[2][NSAMP][64];
  float cbc[4];               // centroid broadcast
};

// 1 block/CU (R17: CU-sharing stretched the fps chain 600->846).
#define SMEM_PAD 90112

// ---------------------------------------------------------------------------
// FUSED fps + ball_dense0 (R18): NO global stores inside the fps step loop —
// R17's per-step OC emit made every barrier drain a contended store
// (vmcnt(0) before s_barrier, ~120cyc/step under consumer traffic).
// Centroids now buffered in LDS (sidx) and emitted in 32-chunks by t0,
// followed by the RELEASE/AGENT progress publish. Consumers unchanged.
// ---------------------------------------------------------------------------
__global__ __launch_bounds__(256)
void fps_ball_kernel(const float* __restrict__ xyz, const float* __restrict__ pts,
                     const float* __restrict__ W0, const float* __restrict__ b0v,
                     float* __restrict__ cent, float* __restrict__ y0,
                     float* __restrict__ psum, float* __restrict__ psq,
                     int* __restrict__ ctl) {
  __shared__ int s_tk;
  __shared__ int s_cnt;
  __shared__ alignas(16) unsigned char smem[SMEM_PAD];   // 1 block/CU
  const int t = threadIdx.x;
  if (t == 0) s_tk = atomicAdd(&ctl[0], 1);
  __syncthreads();
  const int tk = s_tk;

  if (tk < NB) {
    // ================= FPS role (batch = tk) =================
    FpsShared& S = *reinterpret_cast<FpsShared*>(smem);
    const int b = tk;
    const float* X = xyz + (size_t)b * NPTS * 3;
    float* OC = cent + (size_t)b * NC * 3;
    int* prog = ctl + 16 + 16 * b;              // own cacheline

    for (int p = t; p < NPTS; p += 256)
      S.sxyz[p] = make_float4(X[p * 3 + 0], X[p * 3 + 1], X[p * 3 + 2], 0.f);
    __syncthreads();

    float px[16], py[16], pz[16], h[16];
    #pragma unroll
    for (int i = 0; i < 16; i++) {
      float4 v = S.sxyz[t * 16 + i];
      px[i] = v.x; py[i] = v.y; pz[i] = v.z;
      h[i] = fmaf(v.x, v.x, fmaf(v.y, v.y, v.z * v.z));   // |p|^2
    }

    const int wv = t >> 6;
    float4 c;

    auto step_body = [&](int pw_) {
      const float c2x = c.x + c.x, c2y = c.y + c.y, c2z = c.z + c.z;
      float key[16]; int idx[16];
      #pragma unroll
      for (int i = 0; i < 16; i++) {
        key[i] = fmaf(pz[i], -c2z, fmaf(py[i], -c2y, fmaf(px[i], -c2x, h[i])));
        idx[i] = i;
      }
      #pragma unroll
      for (int s = 1; s < 16; s <<= 1) {        // tree argmax, first-max ties
        #pragma unroll
        for (int i = 0; i < 16; i += 2 * s) {
          bool tkn = key[i + s] > key[i];
          key[i] = tkn ? key[i + s] : key[i];
          idx[i] = tkn ? idx[i + s] : idx[i];
        }
      }
      const float mx = key[0];
      const int mj = idx[0];
      float4 cand = S.sxyz[(t << 4) + mj];      // speculative; hides under reduce
      float wm = wave64_fmax(mx);
      float smax = __int_as_float(__builtin_amdgcn_readlane(__float_as_int(wm), 63));
      if (mx == smax) {
        S.wkc[pw_][wv] = make_float4(cand.x, cand.y, cand.z, smax);
        S.wki[pw_][wv] = (t << 4) + mj;
      }
    };

    auto fold = [&](int pr_) -> int {
      float4 q0 = S.wkc[pr_][0], q1 = S.wkc[pr_][1];
      float4 q2 = S.wkc[pr_][2], q3 = S.wkc[pr_][3];
      const int4 ii = *(const int4*)&S.wki[pr_][0];
      bool g1 = q1.w > q0.w; float4 ca = g1 ? q1 : q0; int ia = g1 ? ii.y : ii.x;
      bool g3 = q3.w > q2.w; float4 cb = g3 ? q3 : q2; int ib = g3 ? ii.w : ii.z;
      bool gb = cb.w > ca.w; c = gb ? cb : ca; return gb ? ib : ia;
    };

    // emit selections [j0, j1) from LDS to OC, then publish prog=j1 (t0 only)
    auto emit_chunk = [&](int j0, int j1) {
      for (int j = j0; j < j1; j++) {
        float4 cc = S.sxyz[S.sidx[j]];
        OC[j * 3 + 0] = cc.x;
        OC[j * 3 + 1] = cc.y;
        OC[j * 3 + 2] = cc.z;
      }
      __hip_atomic_store(prog, j1, __ATOMIC_RELEASE, __HIP_MEMORY_SCOPE_AGENT);
    };

    // ---- iteration 1: selection 0 is point 0 (seed) ----
    c = S.sxyz[0];
    if (t == 0) {
      h[0] = -__builtin_inff();                 // retire point 0 (t0 owns it)
      S.sidx[0] = 0;
    }
    step_body(1);
    __syncthreads();

    for (int k = 2; k < NC; k++) {
      const int pr = (k - 1) & 1, pw = k & 1;
      int gidx = fold(pr);                      // selection k-1
      if (t == 0) {
        S.sidx[k - 1] = gidx;                   // LDS only — no global store
        if (((k - 1) & 31) == 31)               // chunk boundary: batch emit
          emit_chunk(k - 32, k);
      }
      if ((gidx >> 4) == t) {                   // retire: -INF loses everything
        int m = gidx & 15;
        #pragma unroll
        for (int i = 0; i < 16; i++)
          if (i == m) h[i] = -__builtin_inff();
      }
      step_body(pw);
      __syncthreads();
    }
    {                                           // epilogue: selection 1023
      int gidx = fold(1023 & 1);
      if (t == 0) {
        S.sidx[NC - 1] = gidx;
        emit_chunk(NC - 32, NC);                // final chunk (992..1023)
      }
    }
  } else {
    // ================= BALL+DENSE0 role =================
    BallShared& S = *reinterpret_cast<BallShared*>(smem);
    const int id = tk - NB;
    const int cc = id >> 3;                     // c-major: track fps frontier
    const int b = id & 7;
    const int blk = (b << 10) | cc;
    const float* X = xyz + (size_t)b * NPTS * 3;
    const float* P = pts + (size_t)b * NPTS * DP;
    int* prog = ctl + 16 + 16 * b;

    if (t == 0) s_cnt = 0;
    for (int e = t; e < C0 * 64; e += 256) S.w0s[e] = W0[e];  // stage pre-spin
    if (t < 64) S.b0s[t] = b0v[t];

    if (t == 0) {                               // ACQUIRE spin, sleep-throttled
      while (__hip_atomic_load(prog, __ATOMIC_ACQUIRE, __HIP_MEMORY_SCOPE_AGENT) < cc + 1)
        __builtin_amdgcn_s_sleep(32);
      S.cbc[0] = cent[(size_t)blk * 3 + 0];     // post-acquire reads (t0 only)
      S.cbc[1] = cent[(size_t)blk * 3 + 1];
      S.cbc[2] = cent[(size_t)blk * 3 + 2];
    }
    __syncthreads();
    const float cx = S.cbc[0], cy = S.cbc[1], cz = S.cbc[2];

    // vectorized scan: 12x float4/thread; packed exact no-FMA distances
    {
      float4 xb[12];
      const float4* Xv = (const float4*)(X + (size_t)t * 48);
      #pragma unroll
      for (int i = 0; i < 12; i++) xb[i] = Xv[i];
      const float* xf = (const float*)xb;       // compile-time indices only
      v2f sq2[8];
      {
        #pragma clang fp contract(off)
        const v2f c2x = v2f{cx, cx}, c2y = v2f{cy, cy}, c2z = v2f{cz, cz};
        #pragma unroll
        for (int i = 0; i < 8; i++) {           // pair = points 2i, 2i+1
          v2f x2 = v2f{xf[6 * i + 0], xf[6 * i + 3]};
          v2f y2 = v2f{xf[6 * i + 1], xf[6 * i + 4]};
          v2f z2 = v2f{xf[6 * i + 2], xf[6 * i + 5]};
          v2f dx = x2 - c2x, dy = y2 - c2y, dz = z2 - c2z;
          sq2[i] = (dx * dx + dy * dy) + dz * dz;
        }
      }
      #pragma unroll
      for (int i = 0; i < 16; i++) {
        int j = t * 16 + i;
        float sq = (i & 1) ? sq2[i >> 1].y : sq2[i >> 1].x;
        if (sq < 0.0017f) {                     // conservative guard
          float d = (sq > 0.f) ? sqrtf(sq) : 0.f;
          if (d < 0.04f) {                      // strictly inside the clip value
            int pos = atomicAdd(&s_cnt, 1);
            if (pos < BCAP)
              S.skeys[pos] = ((ull)(unsigned)__float_as_int(d) << 12) | (unsigned)j;
          }
        }
      }
    }
    __syncthreads();
    const int M = min(s_cnt, BCAP);

    if (t < M) {                                // rank-sort inner set
      ull my = S.skeys[t];
      int r = 0;
      for (int j2 = 0; j2 < M; j2++) r += (S.skeys[j2] < my);
      S.ssorted[r] = my;
    }
    __syncthreads();

    if (t < NSAMP) {
      int v;
      if (t < M) {
        v = (int)(S.ssorted[t] & 0xFFFull);
      } else {
        int s = t - M;                          // s-th smallest non-inner index
        int idx = s;
        for (int it = 0; it < 40; it++) {
          int cnum = 0;
          for (int j2 = 0; j2 < M; j2++) cnum += ((int)(S.skeys[j2] & 0xFFFull) <= idx);
          int nidx = s + cnum;
          if (nidx == idx) break;
          idx = nidx;
        }
        v = idx;
      }
      S.sel[t] = v;
    }
    __syncthreads();

    for (int e = t; e < NSAMP * C0; e += 256) {
      int k = e / C0;
      int ccc = e - k * C0;
      int j = S.sel[k];
      S.xs0[e] = (ccc < 3) ? X[j * 3 + ccc] : P[j * DP + (ccc - 3)];
    }
    __syncthreads();

    const int row = t >> 3, c8 = (t & 7) * 8;
    float a[8];
    #pragma unroll
    for (int j = 0; j < 8; j++) a[j] = S.b0s[c8 + j];
    #pragma unroll
    for (int k = 0; k < C0; k++) {
      float xv = S.xs0[row * C0 + k];
      #pragma unroll
      for (int j = 0; j < 8; j++) a[j] = fmaf(xv, S.w0s[k * 64 + c8 + j], a[j]);
    }
    float* Y = y0 + ((size_t)blk * NSAMP + row) * 64 + c8;
    *(float4*)(Y + 0) = make_float4(a[0], a[1], a[2], a[3]);
    *(float4*)(Y + 4) = make_float4(a[4], a[5], a[6], a[7]);
    #pragma unroll
    for (int j = 0; j < 8; j++) S.red[0][row][c8 + j] = a[j];
    #pragma unroll
    for (int j = 0; j < 8; j++) S.red[1][row][c8 + j] = a[j] * a[j];
    __syncthreads();
    if (t < 64) {
      float Ss = 0.f, Q = 0.f;
      #pragma unroll
      for (int g = 0; g < NSAMP; g++) { Ss += S.red[0][g][t]; Q += S.red[1][g][t]; }
      psum[(size_t)t * 8192 + blk] = Ss;
      psq [(size_t)t * 8192 + blk] = Q;
    }
  }
}

// ---------------------------------------------------------------------------
// dense layer 1, LANE-PER-ROW (unchanged R13)
// ---------------------------------------------------------------------------
__global__ __launch_bounds__(256)
void dense_lane1_kernel(const float* __restrict__ y0, const float* __restrict__ ss0,
                        const float* __restrict__ W1, const float* __restrict__ b1,
                        float* __restrict__ y1,
                        float* __restrict__ psum, float* __restrict__ psq) {
  __shared__ float tr[4][64][33];
  __shared__ float wred[2][4][64];
  const int t = threadIdx.x, wid = t >> 6, lane = t & 63;
  const size_t row = (size_t)blockIdx.x * 256 + (size_t)(wid * 64 + lane);
  float acc[64];
  #pragma unroll
  for (int c = 0; c < 64; c++) acc[c] = b1[c];
  const float* Xr = y0 + row * 64;
  #pragma unroll 1
  for (int k0 = 0; k0 < 64; k0 += 4) {
    float4 xv = *(const float4*)(Xr + k0);
    #pragma unroll
    for (int kk = 0; kk < 4; kk++) {
      const int k = k0 + kk;
      float x = fmaxf(fmaf((&xv.x)[kk], ss0[k], ss0[128 + k]), 0.f);
      const float* Wk = W1 + k * 64;
      #pragma unroll
      for (int c = 0; c < 64; c++) acc[c] = fmaf(x, Wk[c], acc[c]);
    }
  }
  float* Yr = y1 + row * 64;
  #pragma unroll
  for (int c0 = 0; c0 < 64; c0 += 4)
    *(float4*)(Yr + c0) = make_float4(acc[c0], acc[c0 + 1], acc[c0 + 2], acc[c0 + 3]);
  const int c = lane & 31;
  const bool isQ = lane >= 32;
  #pragma unroll
  for (int chunk = 0; chunk < 2; chunk++) {
    __syncthreads();
    #pragma unroll
    for (int j = 0; j < 32; j++) tr[wid][lane][j] = acc[chunk * 32 + j];
    __syncthreads();
    float A = 0.f;
    for (int r = 0; r < 64; r++) {
      float v = tr[wid][r][c];
      A = fmaf(v, isQ ? v : 1.0f, A);
    }
    wred[isQ ? 1 : 0][wid][chunk * 32 + c] = A;
  }
  __syncthreads();
  if (t < 64) {
    float S = 0.f, Q = 0.f;
    #pragma unroll
    for (int w = 0; w < 4; w++) { S += wred[0][w][t]; Q += wred[1][w][t]; }
    psum[(size_t)t * 1024 + blockIdx.x] = S;
    psq [(size_t)t * 1024 + blockIdx.x] = Q;
  }
}

// ---------------------------------------------------------------------------
// dense layer 2, LANE-PER-ROW (unchanged R13)
// ---------------------------------------------------------------------------
__global__ __launch_bounds__(256)
void dense_lane2_kernel(const float* __restrict__ y1, const float* __restrict__ ss1,
                        const float* __restrict__ W2, const float* __restrict__ b2,
                        float* __restrict__ psum, float* __restrict__ psq,
                        float* __restrict__ gmax, float* __restrict__ gmin) {
  __shared__ float tr[4][64][33];
  __shared__ float wred[2][4][128];
  const int t = threadIdx.x, wid = t >> 6, lane = t & 63;
  const size_t row = (size_t)blockIdx.x * 256 + (size_t)(wid * 64 + lane);
  const int centA = blockIdx.x * 8 + wid * 2;
  const int centB = centA + 1;

  float x[64];
  const float* Xr = y1 + row * 64;
  #pragma unroll
  for (int k0 = 0; k0 < 64; k0 += 4) {
    float4 xv = *(const float4*)(Xr + k0);
    #pragma unroll
    for (int kk = 0; kk < 4; kk++)
      x[k0 + kk] = fmaxf(fmaf((&xv.x)[kk], ss1[k0 + kk], ss1[128 + k0 + kk]), 0.f);
  }

  const int c = lane & 31;
  const bool isQ = lane >= 32;
  #pragma unroll 1
  for (int half = 0; half < 2; half++) {
    float acc[64];
    #pragma unroll
    for (int cc = 0; cc < 64; cc++) acc[cc] = b2[half * 64 + cc];
    #pragma unroll 1
    for (int k = 0; k < 64; k++) {
      const float* Wk = W2 + k * C3 + half * 64;
      const float xk = x[k];
      #pragma unroll
      for (int cc = 0; cc < 64; cc++) acc[cc] = fmaf(xk, Wk[cc], acc[cc]);
    }
    #pragma unroll
    for (int chunk = 0; chunk < 2; chunk++) {
      __syncthreads();
      #pragma unroll
      for (int j = 0; j < 32; j++) tr[wid][lane][j] = acc[chunk * 32 + j];
      __syncthreads();
      const int ch = half * 64 + chunk * 32 + c;
      float A = 0.f, m1 = -__builtin_inff(), m2 = -__builtin_inff();
      for (int r = 0; r < 32; r++) {
        float v = tr[wid][r][c];
        A = fmaf(v, isQ ? v : 1.0f, A);
        m1 = fmaxf(m1, isQ ? -v : v);
      }
      for (int r = 32; r < 64; r++) {
        float v = tr[wid][r][c];
        A = fmaf(v, isQ ? v : 1.0f, A);
        m2 = fmaxf(m2, isQ ? -v : v);
      }
      wred[isQ ? 1 : 0][wid][ch] = A;
      if (!isQ) {
        gmax[(size_t)centA * C3 + ch] = m1;
        gmax[(size_t)centB * C3 + ch] = m2;
      } else {
        gmin[(size_t)centA * C3 + ch] = -m1;
        gmin[(size_t)centB * C3 + ch] = -m2;
      }
    }
  }
  __syncthreads();
  if (t < C3) {
    float S = 0.f, Q = 0.f;
    #pragma unroll
    for (int w = 0; w < 4; w++) { S += wred[0][w][t]; Q += wred[1][w][t]; }
    psum[(size_t)t * 1024 + blockIdx.x] = S;
    psq [(size_t)t * 1024 + blockIdx.x] = Q;
  }
}

// ---------------------------------------------------------------------------
// stats finalize (unchanged)
// ---------------------------------------------------------------------------
template <int NBLK>
__global__ __launch_bounds__(256)
void stats_final_kernel(const float* __restrict__ psum, const float* __restrict__ psq,
                        const float* __restrict__ g, const float* __restrict__ be,
                        float* __restrict__ ss_out) {
  const int c = blockIdx.x, t = threadIdx.x;
  float S = 0.f, Q = 0.f;
  for (int i = t; i < NBLK; i += 256) {
    S += psum[(size_t)c * NBLK + i];
    Q += psq [(size_t)c * NBLK + i];
  }
  __shared__ float sS[256], sQ[256];
  sS[t] = S; sQ[t] = Q;
  __syncthreads();
  #pragma unroll
  for (int off = 128; off; off >>= 1) {
    if (t < off) { sS[t] += sS[t + off]; sQ[t] += sQ[t + off]; }
    __syncthreads();
  }
  if (t == 0) {
    const float inv = 1.0f / 262144.0f;
    float mean = sS[0] * inv;
    float var = sQ[0] * inv - mean * mean;
    float scale = g[c] / sqrtf(var + 1e-3f);
    ss_out[c] = scale;
    ss_out[128 + c] = be[c] - mean * scale;
  }
}

// pool finalize (unchanged)
__global__ __launch_bounds__(128)
void pool_final_kernel(const float* __restrict__ gmax, const float* __restrict__ gmin,
                       const float* __restrict__ ss2, float* __restrict__ out1) {
  const int blk = blockIdx.x, c = threadIdx.x;
  const float sc = ss2[c], sh = ss2[128 + c];
  float v = (sc >= 0.f) ? gmax[(size_t)blk * C3 + c] : gmin[(size_t)blk * C3 + c];
  out1[(size_t)blk * C3 + c] = fmaxf(fmaf(v, sc, sh), 0.f);
}

extern "C" void kernel_launch(void* const* d_in, const int* in_sizes, int n_in,
                              void* d_out, int out_size, void* d_ws, size_t ws_size,
                              hipStream_t stream) {
  const float* xyz = (const float*)d_in[0];
  const float* pts = (const float*)d_in[1];
  const float* w0 = (const float*)d_in[2];
  const float* b0 = (const float*)d_in[3];
  const float* g0 = (const float*)d_in[4];
  const float* be0 = (const float*)d_in[5];
  const float* w1 = (const float*)d_in[6];
  const float* b1 = (const float*)d_in[7];
  const float* g1 = (const float*)d_in[8];
  const float* be1 = (const float*)d_in[9];
  const float* w2 = (const float*)d_in[10];
  const float* b2 = (const float*)d_in[11];
  const float* g2 = (const float*)d_in[12];
  const float* be2 = (const float*)d_in[13];

  float* out = (float*)d_out;
  float* cent = out;                       // [8,1024,3]
  float* out1 = out + (size_t)NB * NC * 3; // [8,1024,128]

  char* ws = (char*)d_ws;
  int*   ctl  = (int*)ws;                  // ticket ctr + prog[8]
  float* ssA  = (float*)(ws + OFF_SS);
  float* y0   = (float*)(ws + OFF_Y0);
  float* y1   = (float*)(ws + OFF_Y1);
  float* psum = (float*)(ws + OFF_PSUM);
  float* psq  = (float*)(ws + OFF_PSQ);
  float* gmx  = (float*)(ws + OFF_GMX);
  float* gmn  = (float*)(ws + OFF_GMN);

  hipMemsetAsync(ctl, 0, 1024, stream);    // reset tickets + progress each call

  fps_ball_kernel<<<dim3(NB + NB * NC), dim3(256), 0, stream>>>(
      xyz, pts, w0, b0, cent, y0, psum, psq, ctl);
  stats_final_kernel<8192><<<dim3(64), dim3(256), 0, stream>>>(psum, psq, g0, be0, ssA + 0 * 256);

  dense_lane1_kernel<<<dim3(ROWS_TOT / 256), dim3(256), 0, stream>>>(
      y0, ssA + 0 * 256, w1, b1, y1, psum, psq);
  stats_final_kernel<1024><<<dim3(64), dim3(256), 0, stream>>>(psum, psq, g1, be1, ssA + 1 * 256);

  dense_lane2_kernel<<<dim3(ROWS_TOT / 256), dim3(256), 0, stream>>>(
      y1, ssA + 1 * 256, w2, b2, psum, psq, gmx, gmn);
  stats_final_kernel<1024><<<dim3(128), dim3(256), 0, stream>>>(psum, psq, g2, be2, ssA + 2 * 256);

  pool_final_kernel<<<dim3(NB * NC), dim3(128), 0, stream>>>(gmx, gmn, ssA + 2 * 256, out1);

  (void)in_sizes; (void)n_in; (void)out_size; (void)ws_size;
}

// Round 19
// 807.255 us; speedup vs baseline: 1.1047x; 1.1047x over previous
//
#include <hip/hip_runtime.h>

// Problem constants (B=8, N=4096, n_points=1024, n_samples=32, D_PTS=6, MLPS=[64,64,128])
#define NPTS  4096
#define NB    8
#define NC    1024
#define NSAMP 32
#define DP    6
#define C0    9      // 3 + D_PTS
#define C3    128
#define ROWS_TOT 262144   // NB*NC*NSAMP

// Workspace layout (bytes). Requires ws_size >= ~184 MB.
#define OFF_SS   (32ull<<10)     // 3 layers x {scale[128], shift[128]}
#define OFF_Y0   (16ull<<20)     // y0: 262144 x 64 f32 (67 MB)
#define OFF_Y1   (96ull<<20)     // y1: 262144 x 64 f32 (67 MB)
#define OFF_PSUM (168ull<<20)    // per-block channel sums   [C][NBLK]
#define OFF_PSQ  (172ull<<20)    // per-block channel sumsq  [C][NBLK]
#define OFF_GMX  (176ull<<20)    // per-centroid channel max [8192][128]
#define OFF_GMN  (180ull<<20)    // per-centroid channel min [8192][128]

typedef unsigned long long ull;
typedef float v2f __attribute__((ext_vector_type(2)));

// Exact (no-FMA) squared distance to match numpy rounding; sum order ((x+y)+z).
__device__ __forceinline__ float sqdist_noc(float x, float y, float z,
                                            float cx, float cy, float cz) {
  #pragma clang fp contract(off)
  float dx = x - cx, dy = y - cy, dz = z - cz;
  return dx * dx + dy * dy + dz * dz;
}

// DPP move with old=self (masked/invalid lanes keep their value -> fmax identity)
template <int CTRL, int RM>
__device__ __forceinline__ float dpp_mov_f(float x) {
  int xi = __float_as_int(x);
  int r = __builtin_amdgcn_update_dpp(xi, xi, CTRL, RM, 0xf, false);
  return __int_as_float(r);
}

// Canonical gfx9 wave64 f32 max reduce; result valid in lane 63.
__device__ __forceinline__ float wave64_fmax(float x) {
  x = fmaxf(x, dpp_mov_f<0x111, 0xf>(x));  // row_shr:1
  x = fmaxf(x, dpp_mov_f<0x112, 0xf>(x));  // row_shr:2
  x = fmaxf(x, dpp_mov_f<0x114, 0xf>(x));  // row_shr:4
  x = fmaxf(x, dpp_mov_f<0x118, 0xf>(x));  // row_shr:8
  x = fmaxf(x, dpp_mov_f<0x142, 0xa>(x));  // row_bcast:15 -> rows 1,3
  x = fmaxf(x, dpp_mov_f<0x143, 0xc>(x));  // row_bcast:31 -> rows 2,3
  return x;
}

// ---------------------------------------------------------------------------
// FPS (R8 structure — measured 600.4 us across four rounds; every structural
// variant regressed: 512thr R12 +135, 1-wave R10 +catastrophic, 2-batch R9
// +148, fused-overlap R16/17/18 +120..150 on the chain):
// 256 thr / 4 waves, 16 pts/thread; tree argmax; f32 DPP reduce; speculative
// candidate-coord read; coords+key parity exchange; 1 barrier/step.
// ---------------------------------------------------------------------------
__global__ __launch_bounds__(256)
void fps_kernel(const float* __restrict__ xyz, float* __restrict__ cent) {
  const int b = blockIdx.x;
  const int t = threadIdx.x;
  const float* X = xyz + (size_t)b * NPTS * 3;
  float* OC = cent + (size_t)b * NC * 3;

  __shared__ float4 sxyz[NPTS];                 // 64 KB
  __shared__ float4 wkc[2][4];                  // per-wave (x,y,z,key), parity-dbuf
  __shared__ alignas(16) int wki[2][4];         // per-wave winner gidx
  __shared__ int sidx[NC];                      // 4 KB

  for (int p = t; p < NPTS; p += 256)
    sxyz[p] = make_float4(X[p * 3 + 0], X[p * 3 + 1], X[p * 3 + 2], 0.f);
  __syncthreads();

  float px[16], py[16], pz[16], h[16];
  #pragma unroll
  for (int i = 0; i < 16; i++) {
    float4 v = sxyz[t * 16 + i];
    px[i] = v.x; py[i] = v.y; pz[i] = v.z;
    h[i] = fmaf(v.x, v.x, fmaf(v.y, v.y, v.z * v.z));   // |p|^2
  }

  const int wv = t >> 6;
  float4 c;   // current centroid (x,y,z,*)

  auto step_body = [&](int pw_) {
    const float c2x = c.x + c.x, c2y = c.y + c.y, c2z = c.z + c.z;
    float key[16]; int idx[16];
    #pragma unroll
    for (int i = 0; i < 16; i++) {
      key[i] = fmaf(pz[i], -c2z, fmaf(py[i], -c2y, fmaf(px[i], -c2x, h[i])));
      idx[i] = i;
    }
    #pragma unroll
    for (int s = 1; s < 16; s <<= 1) {          // tree argmax, first-max ties
      #pragma unroll
      for (int i = 0; i < 16; i += 2 * s) {
        bool tk = key[i + s] > key[i];
        key[i] = tk ? key[i + s] : key[i];
        idx[i] = tk ? idx[i + s] : idx[i];
      }
    }
    const float mx = key[0];
    const int mj = idx[0];
    float4 cand = sxyz[(t << 4) + mj];          // speculative; hides under reduce
    float wm = wave64_fmax(mx);
    float smax = __int_as_float(__builtin_amdgcn_readlane(__float_as_int(wm), 63));
    if (mx == smax) {                           // winner lane(s) of this wave
      wkc[pw_][wv] = make_float4(cand.x, cand.y, cand.z, smax);
      wki[pw_][wv] = (t << 4) + mj;
    }
  };

  auto fold = [&](int pr_) -> int {
    float4 q0 = wkc[pr_][0], q1 = wkc[pr_][1];
    float4 q2 = wkc[pr_][2], q3 = wkc[pr_][3];
    const int4 ii = *(const int4*)&wki[pr_][0];
    bool g1 = q1.w > q0.w; float4 ca = g1 ? q1 : q0; int ia = g1 ? ii.y : ii.x;
    bool g3 = q3.w > q2.w; float4 cb = g3 ? q3 : q2; int ib = g3 ? ii.w : ii.z;
    bool gb = cb.w > ca.w; c = gb ? cb : ca; return gb ? ib : ia;
  };

  // ---- iteration 1: selection 0 is point 0 (seed) ----
  if (t == 0) { sidx[0] = 0; h[0] = -__builtin_inff(); }   // retire point 0
  c = sxyz[0];
  step_body(1);                                 // publish par = 1&1
  __syncthreads();

  for (int k = 2; k < NC; k++) {
    const int pr = (k - 1) & 1, pw = k & 1;
    int gidx = fold(pr);                        // selection k-1
    if (t == 0) sidx[k - 1] = gidx;
    if ((gidx >> 4) == t) {                     // retire: -INF loses everything
      int m = gidx & 15;
      #pragma unroll
      for (int i = 0; i < 16; i++)
        if (i == m) h[i] = -__builtin_inff();
    }
    step_body(pw);
    __syncthreads();
  }
  {                                             // epilogue: selection 1023
    int gidx = fold(1023 & 1);
    if (t == 0) sidx[NC - 1] = gidx;
  }
  __syncthreads();
  for (int i = t; i < NC; i += 256) {           // one-shot centroid emit
    float4 cc = sxyz[sidx[i]];
    OC[i * 3 + 0] = cc.x;
    OC[i * 3 + 1] = cc.y;
    OC[i * 3 + 2] = cc.z;
  }
}

// ---------------------------------------------------------------------------
// ball + dense0 FUSED: vectorized X scan (12x float4/thread) + packed exact
// distances (2 pts/v2f, elementwise sub/mul/add under contract(off) --
// per-component identical to sqdist_noc). h0 never materialized.
// ---------------------------------------------------------------------------
#define BCAP 256
__global__ __launch_bounds__(256)
void ball_dense0_kernel(const float* __restrict__ xyz, const float* __restrict__ pts,
                        const float* __restrict__ cent,
                        const float* __restrict__ W0, const float* __restrict__ b0,
                        float* __restrict__ y0,
                        float* __restrict__ psum, float* __restrict__ psq) {
  const int blk = blockIdx.x;       // b*NC + c
  const int b = blk >> 10;
  const int t = threadIdx.x;
  const float* X = xyz + (size_t)b * NPTS * 3;
  const float* P = pts + (size_t)b * NPTS * DP;
  const float cx = cent[(size_t)blk * 3 + 0];
  const float cy = cent[(size_t)blk * 3 + 1];
  const float cz = cent[(size_t)blk * 3 + 2];

  __shared__ int scount;
  __shared__ ull skeys[BCAP];
  __shared__ ull ssorted[BCAP];
  __shared__ int sel[NSAMP];
  __shared__ float xs0[NSAMP * C0];
  __shared__ float w0s[C0 * 64];
  __shared__ float b0s[64];
  __shared__ float red[2][NSAMP][64];   // 16 KB
  if (t == 0) scount = 0;
  for (int e = t; e < C0 * 64; e += 256) w0s[e] = W0[e];
  if (t < 64) b0s[t] = b0[t];
  __syncthreads();

  // vectorized scan: 16 points = 48 floats = 12 float4 (t*192 B, 16-aligned);
  // distances packed 2 pts/v2f, exact no-FMA per component.
  {
    float4 xb[12];
    const float4* Xv = (const float4*)(X + (size_t)t * 48);
    #pragma unroll
    for (int i = 0; i < 12; i++) xb[i] = Xv[i];
    const float* xf = (const float*)xb;         // compile-time indices only
    v2f sq2[8];
    {
      #pragma clang fp contract(off)
      const v2f c2x = v2f{cx, cx}, c2y = v2f{cy, cy}, c2z = v2f{cz, cz};
      #pragma unroll
      for (int i = 0; i < 8; i++) {             // pair = points 2i, 2i+1
        v2f x2 = v2f{xf[6 * i + 0], xf[6 * i + 3]};
        v2f y2 = v2f{xf[6 * i + 1], xf[6 * i + 4]};
        v2f z2 = v2f{xf[6 * i + 2], xf[6 * i + 5]};
        v2f dx = x2 - c2x, dy = y2 - c2y, dz = z2 - c2z;
        sq2[i] = (dx * dx + dy * dy) + dz * dz;
      }
    }
    #pragma unroll
    for (int i = 0; i < 16; i++) {
      int j = t * 16 + i;
      float sq = (i & 1) ? sq2[i >> 1].y : sq2[i >> 1].x;
      if (sq < 0.0017f) {                       // conservative guard
        float d = (sq > 0.f) ? sqrtf(sq) : 0.f; // exact per-reference norm
        if (d < 0.04f) {                        // strictly inside the clip value
          int pos = atomicAdd(&scount, 1);
          if (pos < BCAP)
            skeys[pos] = ((ull)(unsigned)__float_as_int(d) << 12) | (unsigned)j;
        }
      }
    }
  }
  __syncthreads();
  const int M = min(scount, BCAP);

  if (t < M) {                                // rank-sort inner set
    ull my = skeys[t];
    int r = 0;
    for (int j2 = 0; j2 < M; j2++) r += (skeys[j2] < my);
    ssorted[r] = my;
  }
  __syncthreads();

  if (t < NSAMP) {
    int v;
    if (t < M) {
      v = (int)(ssorted[t] & 0xFFFull);
    } else {
      int s = t - M;                          // s-th smallest non-inner index
      int idx = s;
      for (int it = 0; it < 40; it++) {
        int c = 0;
        for (int j2 = 0; j2 < M; j2++) c += ((int)(skeys[j2] & 0xFFFull) <= idx);
        int nidx = s + c;
        if (nidx == idx) break;
        idx = nidx;
      }
      v = idx;
    }
    sel[t] = v;
  }
  __syncthreads();

  for (int e = t; e < NSAMP * C0; e += 256) {
    int k = e / C0;
    int cc = e - k * C0;
    int j = sel[k];
    xs0[e] = (cc < 3) ? X[j * 3 + cc] : P[j * DP + (cc - 3)];
  }
  __syncthreads();

  const int row = t >> 3, c8 = (t & 7) * 8;
  float a[8];
  #pragma unroll
  for (int j = 0; j < 8; j++) a[j] = b0s[c8 + j];
  #pragma unroll
  for (int k = 0; k < C0; k++) {
    float xv = xs0[row * C0 + k];
    #pragma unroll
    for (int j = 0; j < 8; j++) a[j] = fmaf(xv, w0s[k * 64 + c8 + j], a[j]);
  }
  float* Y = y0 + ((size_t)blk * NSAMP + row) * 64 + c8;
  *(float4*)(Y + 0) = make_float4(a[0], a[1], a[2], a[3]);
  *(float4*)(Y + 4) = make_float4(a[4], a[5], a[6], a[7]);
  #pragma unroll
  for (int j = 0; j < 8; j++) red[0][row][c8 + j] = a[j];
  #pragma unroll
  for (int j = 0; j < 8; j++) red[1][row][c8 + j] = a[j] * a[j];
  __syncthreads();
  if (t < 64) {
    float S = 0.f, Q = 0.f;
    #pragma unroll
    for (int g = 0; g < NSAMP; g++) { S += red[0][g][t]; Q += red[1][g][t]; }
    psum[(size_t)t * 8192 + blk] = S;
    psq [(size_t)t * 8192 + blk] = Q;
  }
}

// ---------------------------------------------------------------------------
// dense layer 1, LANE-PER-ROW (R13)
// ---------------------------------------------------------------------------
__global__ __launch_bounds__(256)
void dense_lane1_kernel(const float* __restrict__ y0, const float* __restrict__ ss0,
                        const float* __restrict__ W1, const float* __restrict__ b1,
                        float* __restrict__ y1,
                        float* __restrict__ psum, float* __restrict__ psq) {
  __shared__ float tr[4][64][33];
  __shared__ float wred[2][4][64];
  const int t = threadIdx.x, wid = t >> 6, lane = t & 63;
  const size_t row = (size_t)blockIdx.x * 256 + (size_t)(wid * 64 + lane);
  float acc[64];
  #pragma unroll
  for (int c = 0; c < 64; c++) acc[c] = b1[c];
  const float* Xr = y0 + row * 64;
  #pragma unroll 1
  for (int k0 = 0; k0 < 64; k0 += 4) {
    float4 xv = *(const float4*)(Xr + k0);
    #pragma unroll
    for (int kk = 0; kk < 4; kk++) {
      const int k = k0 + kk;
      float x = fmaxf(fmaf((&xv.x)[kk], ss0[k], ss0[128 + k]), 0.f);
      const float* Wk = W1 + k * 64;
      #pragma unroll
      for (int c = 0; c < 64; c++) acc[c] = fmaf(x, Wk[c], acc[c]);
    }
  }
  float* Yr = y1 + row * 64;
  #pragma unroll
  for (int c0 = 0; c0 < 64; c0 += 4)
    *(float4*)(Yr + c0) = make_float4(acc[c0], acc[c0 + 1], acc[c0 + 2], acc[c0 + 3]);
  const int c = lane & 31;
  const bool isQ = lane >= 32;
  #pragma unroll
  for (int chunk = 0; chunk < 2; chunk++) {
    __syncthreads();
    #pragma unroll
    for (int j = 0; j < 32; j++) tr[wid][lane][j] = acc[chunk * 32 + j];
    __syncthreads();
    float A = 0.f;
    for (int r = 0; r < 64; r++) {
      float v = tr[wid][r][c];
      A = fmaf(v, isQ ? v : 1.0f, A);
    }
    wred[isQ ? 1 : 0][wid][chunk * 32 + c] = A;
  }
  __syncthreads();
  if (t < 64) {
    float S = 0.f, Q = 0.f;
    #pragma unroll
    for (int w = 0; w < 4; w++) { S += wred[0][w][t]; Q += wred[1][w][t]; }
    psum[(size_t)t * 1024 + blockIdx.x] = S;
    psq [(size_t)t * 1024 + blockIdx.x] = Q;
  }
}

// ---------------------------------------------------------------------------
// dense layer 2, LANE-PER-ROW (R13)
// ---------------------------------------------------------------------------
__global__ __launch_bounds__(256)
void dense_lane2_kernel(const float* __restrict__ y1, const float* __restrict__ ss1,
                        const float* __restrict__ W2, const float* __restrict__ b2,
                        float* __restrict__ psum, float* __restrict__ psq,
                        float* __restrict__ gmax, float* __restrict__ gmin) {
  __shared__ float tr[4][64][33];
  __shared__ float wred[2][4][128];
  const int t = threadIdx.x, wid = t >> 6, lane = t & 63;
  const size_t row = (size_t)blockIdx.x * 256 + (size_t)(wid * 64 + lane);
  const int centA = blockIdx.x * 8 + wid * 2;
  const int centB = centA + 1;

  float x[64];
  const float* Xr = y1 + row * 64;
  #pragma unroll
  for (int k0 = 0; k0 < 64; k0 += 4) {
    float4 xv = *(const float4*)(Xr + k0);
    #pragma unroll
    for (int kk = 0; kk < 4; kk++)
      x[k0 + kk] = fmaxf(fmaf((&xv.x)[kk], ss1[k0 + kk], ss1[128 + k0 + kk]), 0.f);
  }

  const int c = lane & 31;
  const bool isQ = lane >= 32;
  #pragma unroll 1
  for (int half = 0; half < 2; half++) {
    float acc[64];
    #pragma unroll
    for (int cc = 0; cc < 64; cc++) acc[cc] = b2[half * 64 + cc];
    #pragma unroll 1
    for (int k = 0; k < 64; k++) {
      const float* Wk = W2 + k * C3 + half * 64;
      const float xk = x[k];
      #pragma unroll
      for (int cc = 0; cc < 64; cc++) acc[cc] = fmaf(xk, Wk[cc], acc[cc]);
    }
    #pragma unroll
    for (int chunk = 0; chunk < 2; chunk++) {
      __syncthreads();
      #pragma unroll
      for (int j = 0; j < 32; j++) tr[wid][lane][j] = acc[chunk * 32 + j];
      __syncthreads();
      const int ch = half * 64 + chunk * 32 + c;
      float A = 0.f, m1 = -__builtin_inff(), m2 = -__builtin_inff();
      for (int r = 0; r < 32; r++) {
        float v = tr[wid][r][c];
        A = fmaf(v, isQ ? v : 1.0f, A);
        m1 = fmaxf(m1, isQ ? -v : v);
      }
      for (int r = 32; r < 64; r++) {
        float v = tr[wid][r][c];
        A = fmaf(v, isQ ? v : 1.0f, A);
        m2 = fmaxf(m2, isQ ? -v : v);
      }
      wred[isQ ? 1 : 0][wid][ch] = A;
      if (!isQ) {
        gmax[(size_t)centA * C3 + ch] = m1;
        gmax[(size_t)centB * C3 + ch] = m2;
      } else {
        gmin[(size_t)centA * C3 + ch] = -m1;
        gmin[(size_t)centB * C3 + ch] = -m2;
      }
    }
  }
  __syncthreads();
  if (t < C3) {
    float S = 0.f, Q = 0.f;
    #pragma unroll
    for (int w = 0; w < 4; w++) { S += wred[0][w][t]; Q += wred[1][w][t]; }
    psum[(size_t)t * 1024 + blockIdx.x] = S;
    psq [(size_t)t * 1024 + blockIdx.x] = Q;
  }
}

// ---------------------------------------------------------------------------
// stats finalize
// ---------------------------------------------------------------------------
template <int NBLK>
__global__ __launch_bounds__(256)
void stats_final_kernel(const float* __restrict__ psum, const float* __restrict__ psq,
                        const float* __restrict__ g, const float* __restrict__ be,
                        float* __restrict__ ss_out) {
  const int c = blockIdx.x, t = threadIdx.x;
  float S = 0.f, Q = 0.f;
  for (int i = t; i < NBLK; i += 256) {
    S += psum[(size_t)c * NBLK + i];
    Q += psq [(size_t)c * NBLK + i];
  }
  __shared__ float sS[256], sQ[256];
  sS[t] = S; sQ[t] = Q;
  __syncthreads();
  #pragma unroll
  for (int off = 128; off; off >>= 1) {
    if (t < off) { sS[t] += sS[t + off]; sQ[t] += sQ[t + off]; }
    __syncthreads();
  }
  if (t == 0) {
    const float inv = 1.0f / 262144.0f;
    float mean = sS[0] * inv;
    float var = sQ[0] * inv - mean * mean;
    float scale = g[c] / sqrtf(var + 1e-3f);
    ss_out[c] = scale;
    ss_out[128 + c] = be[c] - mean * scale;
  }
}

// pool finalize
__global__ __launch_bounds__(128)
void pool_final_kernel(const float* __restrict__ gmax, const float* __restrict__ gmin,
                       const float* __restrict__ ss2, float* __restrict__ out1) {
  const int blk = blockIdx.x, c = threadIdx.x;
  const float sc = ss2[c], sh = ss2[128 + c];
  float v = (sc >= 0.f) ? gmax[(size_t)blk * C3 + c] : gmin[(size_t)blk * C3 + c];
  out1[(size_t)blk * C3 + c] = fmaxf(fmaf(v, sc, sh), 0.f);
}

extern "C" void kernel_launch(void* const* d_in, const int* in_sizes, int n_in,
                              void* d_out, int out_size, void* d_ws, size_t ws_size,
                              hipStream_t stream) {
  const float* xyz = (const float*)d_in[0];
  const float* pts = (const float*)d_in[1];
  const float* w0 = (const float*)d_in[2];
  const float* b0 = (const float*)d_in[3];
  const float* g0 = (const float*)d_in[4];
  const float* be0 = (const float*)d_in[5];
  const float* w1 = (const float*)d_in[6];
  const float* b1 = (const float*)d_in[7];
  const float* g1 = (const float*)d_in[8];
  const float* be1 = (const float*)d_in[9];
  const float* w2 = (const float*)d_in[10];
  const float* b2 = (const float*)d_in[11];
  const float* g2 = (const float*)d_in[12];
  const float* be2 = (const float*)d_in[13];

  float* out = (float*)d_out;
  float* cent = out;                       // [8,1024,3]
  float* out1 = out + (size_t)NB * NC * 3; // [8,1024,128]

  char* ws = (char*)d_ws;
  float* ssA  = (float*)(ws + OFF_SS);
  float* y0   = (float*)(ws + OFF_Y0);
  float* y1   = (float*)(ws + OFF_Y1);
  float* psum = (float*)(ws + OFF_PSUM);
  float* psq  = (float*)(ws + OFF_PSQ);
  float* gmx  = (float*)(ws + OFF_GMX);
  float* gmn  = (float*)(ws + OFF_GMN);

  fps_kernel<<<dim3(NB), dim3(256), 0, stream>>>(xyz, cent);

  ball_dense0_kernel<<<dim3(NB * NC), dim3(256), 0, stream>>>(
      xyz, pts, cent, w0, b0, y0, psum, psq);
  stats_final_kernel<8192><<<dim3(64), dim3(256), 0, stream>>>(psum, psq, g0, be0, ssA + 0 * 256);

  dense_lane1_kernel<<<dim3(ROWS_TOT / 256), dim3(256), 0, stream>>>(
      y0, ssA + 0 * 256, w1, b1, y1, psum, psq);
  stats_final_kernel<1024><<<dim3(64), dim3(256), 0, stream>>>(psum, psq, g1, be1, ssA + 1 * 256);

  dense_lane2_kernel<<<dim3(ROWS_TOT / 256), dim3(256), 0, stream>>>(
      y1, ssA + 1 * 256, w2, b2, psum, psq, gmx, gmn);
  stats_final_kernel<1024><<<dim3(128), dim3(256), 0, stream>>>(psum, psq, g2, be2, ssA + 2 * 256);

  pool_final_kernel<<<dim3(NB * NC), dim3(128), 0, stream>>>(gmx, gmn, ssA + 2 * 256, out1);

  (void)in_sizes; (void)n_in; (void)out_size; (void)ws_size;
}